// Round 5
// baseline (479.085 us; speedup 1.0000x reference)
//
#include <hip/hip_runtime.h>
#include <cstdint>

#define BB 8
#define MM 8192
#define SS 128
#define DD 512
#define QQ 32
#define HH 8
#define HDD 64
#define LN_EPS 1e-5f

typedef __bf16 bf16;
typedef _Float16 f16;
typedef __attribute__((ext_vector_type(8))) __bf16 bf16x8;
typedef __attribute__((ext_vector_type(4))) __bf16 bf16x4;
typedef __attribute__((ext_vector_type(8))) _Float16 f16x8;
typedef __attribute__((ext_vector_type(4))) float f32x4;

#define NEG_INF (-__builtin_inff())

// ---------------- K1: fused pooled + queries(out3) + gates(out2) ----------------
__global__ __launch_bounds__(512) void k_front(const float* __restrict__ ctx,
                                               const float* __restrict__ ctx_w,
                                               const float* __restrict__ ctx_b,
                                               const float* __restrict__ qp,
                                               const float* __restrict__ gate_w,
                                               const float* __restrict__ gate_b,
                                               float* __restrict__ q_out,
                                               float* __restrict__ gates_out) {
    __shared__ float pl[DD];
    __shared__ float scratch[512];
    __shared__ float proj[64];
    int blk = blockIdx.x;
    int b = blk >> 3, js = blk & 7;
    int t = threadIdx.x;
    const float* p = ctx + (size_t)b * SS * DD + t;
    float s = 0.f;
#pragma unroll 8
    for (int i = 0; i < SS; i++) s += p[(size_t)i * DD];
    pl[t] = s * (1.0f / SS);
    __syncthreads();
    int r = js * 64 + (t & 63), ks = t >> 6;
    {
        const f32x4* wr = (const f32x4*)(ctx_w + (size_t)r * DD + ks * 64);
        const f32x4* pv = (const f32x4*)(pl + ks * 64);
        float a = 0.f;
#pragma unroll
        for (int k = 0; k < 16; k++) {
            f32x4 w = wr[k], pp = pv[k];
            a += w.x * pp.x + w.y * pp.y + w.z * pp.z + w.w * pp.w;
        }
        scratch[t] = a;
    }
    __syncthreads();
    if (t < 64) {
        float sum = ctx_b[js * 64 + t];
#pragma unroll
        for (int s8 = 0; s8 < 8; s8++) sum += scratch[t + 64 * s8];
        proj[t] = sum;
    }
    __syncthreads();
    int col = js * 64 + (t & 63);
    float pr = proj[t & 63];
#pragma unroll
    for (int qq = 0; qq < 4; qq++) {
        int q = (t >> 6) * 4 + qq;
        q_out[((size_t)(b * QQ + q)) * DD + col] = qp[q * DD + col] + pr;
    }
    if (js == 0 && t < QQ) {
        const f32x4* gw = (const f32x4*)(gate_w + (size_t)t * DD);
        const f32x4* pv = (const f32x4*)pl;
        float ga = 0.f;
#pragma unroll 8
        for (int k = 0; k < DD / 4; k++) {
            f32x4 w = gw[k], pp = pv[k];
            ga += w.x * pp.x + w.y * pp.y + w.z * pp.z + w.w * pp.w;
        }
        gates_out[b * QQ + t] = 1.0f / (1.0f + __expf(-(ga + gate_b[t])));
    }
}

// ---------------- K4: qh = 0.125 * (queries @ wq^T + bq) ----------------
__global__ __launch_bounds__(256) void k_qh(const float* __restrict__ q_in,
                                            const float* __restrict__ in_w,
                                            const float* __restrict__ in_b,
                                            float* __restrict__ qh) {
    __shared__ float qr[QQ * DD];  // 64 KB
    int blk = blockIdx.x;
    int b = blk >> 3, js = blk & 7;
    int t = threadIdx.x;
    const f32x4* src = (const f32x4*)(q_in + (size_t)b * QQ * DD);
    f32x4* dst = (f32x4*)qr;
    for (int i = t; i < QQ * DD / 4; i += 256) dst[i] = src[i];
    __syncthreads();
    int j = js * 64 + (t & 63);
    int qg = t >> 6;
    const f32x4* wv = (const f32x4*)(in_w + (size_t)j * DD);
    float acc[8];
#pragma unroll
    for (int e = 0; e < 8; e++) acc[e] = 0.f;
    for (int k = 0; k < DD / 4; k++) {
        f32x4 w = wv[k];
#pragma unroll
        for (int e = 0; e < 8; e++) {
            f32x4 qq = ((const f32x4*)qr)[(qg * 8 + e) * (DD / 4) + k];
            acc[e] += w.x * qq.x + w.y * qq.y + w.z * qq.z + w.w * qq.w;
        }
    }
    float bias = in_b[j];
#pragma unroll
    for (int e = 0; e < 8; e++) {
        int q = qg * 8 + e;
        qh[((size_t)(b * QQ + q)) * DD + j] = 0.125f * (acc[e] + bias);
    }
}

// ---------------- K5: combined fp32->bf16 cast (memory + KV weights, one launch) --
#define N4_MEM 8388608
#define N4_W   131072
__global__ __launch_bounds__(256) void k_cvt2(const float* __restrict__ mem,
                                              const float* __restrict__ wsrc,
                                              bf16* __restrict__ memB,
                                              bf16* __restrict__ kvwB) {
    int stride = gridDim.x * blockDim.x;
    for (int i = blockIdx.x * blockDim.x + threadIdx.x; i < N4_MEM + N4_W; i += stride) {
        if (i < N4_MEM) {
            f32x4 v = ((const f32x4*)mem)[i];
            bf16x4 o;
            o.x = (bf16)v.x; o.y = (bf16)v.y; o.z = (bf16)v.z; o.w = (bf16)v.w;
            ((bf16x4*)memB)[i] = o;
        } else {
            int j = i - N4_MEM;
            f32x4 v = ((const f32x4*)wsrc)[j];
            bf16x4 o;
            o.x = (bf16)v.x; o.y = (bf16)v.y; o.z = (bf16)v.z; o.w = (bf16)v.w;
            ((bf16x4*)kvwB)[j] = o;
        }
    }
}

#define GLOAD(gp, lp)                                                                   \
    __builtin_amdgcn_global_load_lds((const __attribute__((address_space(1))) void*)(gp), \
                                     (__attribute__((address_space(3))) void*)(lp), 16, 0, 0)

// ---------------- K7: KV GEMM (proven 92us version): [K|V] = memB @ kvw^T + bias --
// 256x256 tile, BK=64, 512 threads (8 waves). global_load_lds staging both A,B.
// Counted-vmcnt pipeline; outputs K head-major [b][h][m][64] bf16; Vt [b][hd][m] f16.
__global__ __launch_bounds__(512, 2) void k_gemm_kv(const bf16* __restrict__ A,
                                                    const bf16* __restrict__ Bw,
                                                    const float* __restrict__ in_b,
                                                    bf16* __restrict__ Kh,
                                                    f16* __restrict__ Vt) {
    __shared__ __align__(16) bf16 sm[65536];  // 128 KB: 2 x [A 16384 | B 16384]
    const int tid = threadIdx.x;
    const int w = tid >> 6, l = tid & 63;
    const int wm = w >> 2, wn = w & 3;
    const int lq = l & 15, quad = l >> 4, lx = l & 7;
    const int lr = l >> 3, gc = (l & 7) ^ lr;
    const int sb = (w >> 1) * 8 + (w & 1) * 2;

    const int bid = blockIdx.x;                    // 1024 blocks
    const int swz = (bid & 7) * 128 + (bid >> 3);  // XCD-contiguous chunks
    const int bm = swz >> 2, bn = swz & 3;

    const bf16* aPtr = A + (size_t)(bm * 256 + w * 8 + lr) * 512 + gc * 8;
    const bf16* bPtr = Bw + (size_t)(bn * 256 + sb * 8 + lr) * 512 + gc * 8;

    // prologue: tile 0 into buf 0. A x4, then B-low x2, then B-high x2.
#pragma unroll
    for (int p = 0; p < 4; p++) GLOAD(aPtr + p * 32768, sm + (p * 8 + w) * 512);
#pragma unroll
    for (int p = 0; p < 4; p++) {
        GLOAD(bPtr + ((p & 1) * 8 + (p >> 1) * 32) * 512,
              sm + 16384 + (sb + (p & 1) + (p >> 1) * 4) * 512);
        if (p == 1) __builtin_amdgcn_sched_barrier(0);
    }
    aPtr += 64;
    bPtr += 64;

    const f32x4 vzero = {0.f, 0.f, 0.f, 0.f};
    f32x4 acc[8][4];
#pragma unroll
    for (int i = 0; i < 8; i++)
#pragma unroll
        for (int j = 0; j < 4; j++) acc[i][j] = vzero;

#pragma unroll
    for (int T = 0; T < 8; T++) {
        bf16* Ab = sm + (T & 1) * 32768;
        bf16* Bb = Ab + 16384;
        bf16* AbN = sm + ((T + 1) & 1) * 32768;
        bf16* BbN = AbN + 16384;
        const bool pf = (T < 7);

        // ===== phase 0: A-frags + B cols 0,1; prefetch A(T+1) =====
        asm volatile("s_waitcnt vmcnt(2)" ::: "memory");
        __builtin_amdgcn_s_barrier();
        bf16x8 af[8][2], b01[2][2];
        {
            const int c0 = (quad ^ lx) << 3;
#pragma unroll
            for (int i = 0; i < 8; i++) {
                const bf16* rp = Ab + (wm * 128 + i * 16 + lq) * 64;
                af[i][0] = *(const bf16x8*)(rp + c0);
                af[i][1] = *(const bf16x8*)(rp + (c0 ^ 32));
            }
#pragma unroll
            for (int j = 0; j < 2; j++) {
                const bf16* rp = Bb + (wn * 64 + j * 16 + lq) * 64;
                b01[j][0] = *(const bf16x8*)(rp + c0);
                b01[j][1] = *(const bf16x8*)(rp + (c0 ^ 32));
            }
        }
        if (pf) {
#pragma unroll
            for (int p = 0; p < 4; p++) GLOAD(aPtr + p * 32768, AbN + (p * 8 + w) * 512);
            aPtr += 64;
        }
        __builtin_amdgcn_s_setprio(1);
#pragma unroll
        for (int i = 0; i < 8; i++)
#pragma unroll
            for (int j = 0; j < 2; j++) {
                acc[i][j] = __builtin_amdgcn_mfma_f32_16x16x32_bf16(af[i][0], b01[j][0], acc[i][j], 0, 0, 0);
                acc[i][j] = __builtin_amdgcn_mfma_f32_16x16x32_bf16(af[i][1], b01[j][1], acc[i][j], 0, 0, 0);
            }
        __builtin_amdgcn_s_setprio(0);

        // ===== phase 1: B cols 2,3; prefetch B(T+1) =====
        if (pf) {
            asm volatile("s_waitcnt vmcnt(4)" ::: "memory");
        } else {
            asm volatile("s_waitcnt vmcnt(0)" ::: "memory");
        }
        __builtin_amdgcn_s_barrier();
        bf16x8 b23[2][2];
        {
            const int c0 = (quad ^ lx) << 3;
#pragma unroll
            for (int j = 0; j < 2; j++) {
                const bf16* rp = Bb + (wn * 64 + 32 + j * 16 + lq) * 64;
                b23[j][0] = *(const bf16x8*)(rp + c0);
                b23[j][1] = *(const bf16x8*)(rp + (c0 ^ 32));
            }
        }
        if (pf) {
#pragma unroll
            for (int p = 0; p < 4; p++) {
                GLOAD(bPtr + ((p & 1) * 8 + (p >> 1) * 32) * 512,
                      BbN + (sb + (p & 1) + (p >> 1) * 4) * 512);
                if (p == 1) __builtin_amdgcn_sched_barrier(0);
            }
            bPtr += 64;
        }
        __builtin_amdgcn_s_setprio(1);
#pragma unroll
        for (int i = 0; i < 8; i++)
#pragma unroll
            for (int j = 0; j < 2; j++) {
                acc[i][2 + j] = __builtin_amdgcn_mfma_f32_16x16x32_bf16(af[i][0], b23[j][0], acc[i][2 + j], 0, 0, 0);
                acc[i][2 + j] = __builtin_amdgcn_mfma_f32_16x16x32_bf16(af[i][1], b23[j][1], acc[i][2 + j], 0, 0, 0);
            }
        __builtin_amdgcn_s_setprio(0);
    }

    // ---- epilogue through LDS: 4 quadrants of 128x128 in parallel (128 KB) ----
    __syncthreads();
    const int qn_w = wn >> 1;
    bf16* qt = sm + (((wm << 1) | qn_w) * 16384);
    const bool isV = (bn >= 2);
    if (!isV) {
        // K quadrants: row-major tile, col-chunk swizzled by row (bf16)
#pragma unroll
        for (int j = 0; j < 4; j++) {
            int cq = (wn & 1) * 64 + j * 16 + lq;
            float bias = in_b[512 + bn * 256 + qn_w * 128 + cq];
            int cc = cq >> 3, cl = cq & 7;
#pragma unroll
            for (int i = 0; i < 8; i++) {
                int rb = i * 16 + quad * 4;
#pragma unroll
                for (int t = 0; t < 4; t++) {
                    int r = rb + t;
                    qt[r * 128 + (((cc ^ (r & 15)) << 3) | cl)] = (bf16)(acc[i][j][t] + bias);
                }
            }
        }
        __syncthreads();
        for (int idx = tid; idx < 8192; idx += 512) {
            int qq2 = idx >> 11;
            int rr = (idx >> 4) & 127, ch2 = idx & 15;
            bf16x8 v = *(const bf16x8*)(sm + qq2 * 16384 + rr * 128 + ((ch2 ^ (rr & 15)) << 3));
            int m = bm * 256 + (qq2 >> 1) * 128 + rr;
            int cg = bn * 256 + (qq2 & 1) * 128 + ch2 * 8;
            int b = m >> 13, mloc = m & 8191;
            int h = cg >> 6, d = cg & 63;
            *(bf16x8*)(Kh + (((size_t)(b * 8 + h) * 8192 + mloc) << 6) + d) = v;
        }
    } else {
        // V quadrants: transposed tile, row-chunk swizzled by col (f16)
        f16* qth = (f16*)qt;
#pragma unroll
        for (int j = 0; j < 4; j++) {
            int cq = (wn & 1) * 64 + j * 16 + lq;
            float bias = in_b[512 + bn * 256 + qn_w * 128 + cq];
            int cs = cq & 15;
#pragma unroll
            for (int i = 0; i < 8; i++) {
                int rb = i * 16 + quad * 4;
#pragma unroll
                for (int t = 0; t < 4; t++) {
                    int r = rb + t;
                    qth[cq * 128 + ((((r >> 3) ^ cs) << 3) | (r & 7))] = (f16)(acc[i][j][t] + bias);
                }
            }
        }
        __syncthreads();
        for (int idx = tid; idx < 8192; idx += 512) {
            int qq2 = idx >> 11;
            int cq = (idx >> 4) & 127, ch2 = idx & 15;
            f16x8 v = *(const f16x8*)((const f16*)sm + qq2 * 16384 + cq * 128 + ((ch2 ^ (cq & 15)) << 3));
            int hd = (bn - 2) * 256 + (qq2 & 1) * 128 + cq;
            int m = bm * 256 + (qq2 >> 1) * 128 + ch2 * 8;
            int b = m >> 13, mloc = m & 8191;
            *(f16x8*)(Vt + ((size_t)(b * 512 + hd)) * MM + mloc) = v;
        }
    }
}
#undef GLOAD

// ---------------- K8: scores + softmax stats + fused PV partials ----------------
__global__ __launch_bounds__(256) void k_scores(const float* __restrict__ qh,
                                                const bf16* __restrict__ kvK,
                                                const f16* __restrict__ Vt,
                                                const int* __restrict__ mask,
                                                f16* __restrict__ s16,
                                                float* __restrict__ statsM,
                                                float* __restrict__ statsS,
                                                float* __restrict__ cp) {
    __shared__ __align__(16) f16 tile[QQ * 520];
    __shared__ float ctile[QQ * HDD];
    __shared__ float smx[QQ][4];
    __shared__ float sse[QQ][4];
    __shared__ float qmax[QQ];
    int blk = blockIdx.x;  // 1024 = B*H*16
    int mt = blk & 15, h = (blk >> 4) & 7, b = blk >> 7;
    int tid = threadIdx.x, w = tid >> 6, l = tid & 63;
    int lq = l & 15, quad = l >> 4;
    int mbase = mt * 512 + w * 128;

    for (int i = tid; i < QQ * HDD; i += 256) ctile[i] = 0.f;

    bf16x8 af[2][2];
#pragma unroll
    for (int i = 0; i < 2; i++)
#pragma unroll
        for (int s = 0; s < 2; s++) {
            const float* qp = qh + ((size_t)(b * QQ + i * 16 + lq)) * DD + h * 64 + s * 32 + quad * 8;
            f32x4 q0 = *(const f32x4*)qp;
            f32x4 q1 = *(const f32x4*)(qp + 4);
            bf16x8 v;
            v[0] = (bf16)q0.x; v[1] = (bf16)q0.y; v[2] = (bf16)q0.z; v[3] = (bf16)q0.w;
            v[4] = (bf16)q1.x; v[5] = (bf16)q1.y; v[6] = (bf16)q1.z; v[7] = (bf16)q1.w;
            af[i][s] = v;
        }

    const f32x4 vzero = {0.f, 0.f, 0.f, 0.f};
    f32x4 acc[2][8];
#pragma unroll
    for (int i = 0; i < 2; i++)
#pragma unroll
        for (int n = 0; n < 8; n++) acc[i][n] = vzero;

#pragma unroll
    for (int n = 0; n < 8; n++) {
        int m = mbase + n * 16 + lq;
        const bf16* kp = kvK + (((size_t)(b * HH + h) * MM + m) << 6) + quad * 8;
        bf16x8 b0 = *(const bf16x8*)kp;
        bf16x8 b1 = *(const bf16x8*)(kp + 32);
#pragma unroll
        for (int i = 0; i < 2; i++) {
            acc[i][n] = __builtin_amdgcn_mfma_f32_16x16x32_bf16(af[i][0], b0, acc[i][n], 0, 0, 0);
            acc[i][n] = __builtin_amdgcn_mfma_f32_16x16x32_bf16(af[i][1], b1, acc[i][n], 0, 0, 0);
        }
    }
#pragma unroll
    for (int n = 0; n < 8; n++) {
        int mv = mask[b * MM + mbase + n * 16 + lq];
        if (!mv) {
#pragma unroll
            for (int i = 0; i < 2; i++)
#pragma unroll
                for (int t = 0; t < 4; t++) acc[i][n][t] = NEG_INF;
        }
    }
    float mx[2][4];
#pragma unroll
    for (int i = 0; i < 2; i++)
#pragma unroll
        for (int t = 0; t < 4; t++) {
            float m = acc[i][0][t];
#pragma unroll
            for (int n = 1; n < 8; n++) m = fmaxf(m, acc[i][n][t]);
            mx[i][t] = m;
        }
#pragma unroll
    for (int off = 1; off < 16; off <<= 1)
#pragma unroll
        for (int i = 0; i < 2; i++)
#pragma unroll
            for (int t = 0; t < 4; t++) mx[i][t] = fmaxf(mx[i][t], __shfl_xor(mx[i][t], off, 64));
    if (lq == 0) {
#pragma unroll
        for (int i = 0; i < 2; i++)
#pragma unroll
            for (int t = 0; t < 4; t++) smx[i * 16 + quad * 4 + t][w] = mx[i][t];
    }
    __syncthreads();
    if (tid < QQ) qmax[tid] = fmaxf(fmaxf(smx[tid][0], smx[tid][1]), fmaxf(smx[tid][2], smx[tid][3]));
    __syncthreads();
    // p = exp(s - M_c): store to tile (f16) AND accumulate row-sum
    float se[2][4];
#pragma unroll
    for (int i = 0; i < 2; i++)
#pragma unroll
        for (int t = 0; t < 4; t++) {
            int qrow = i * 16 + quad * 4 + t;
            float qm = qmax[qrow];
            float s = 0.f;
#pragma unroll
            for (int n = 0; n < 8; n++) {
                float p = __expf(acc[i][n][t] - qm);
                s += p;
                tile[qrow * 520 + w * 128 + n * 16 + lq] = (f16)p;
            }
            se[i][t] = s;
        }
#pragma unroll
    for (int off = 1; off < 16; off <<= 1)
#pragma unroll
        for (int i = 0; i < 2; i++)
#pragma unroll
            for (int t = 0; t < 4; t++) se[i][t] += __shfl_xor(se[i][t], off, 64);
    if (lq == 0) {
#pragma unroll
        for (int i = 0; i < 2; i++)
#pragma unroll
            for (int t = 0; t < 4; t++) sse[i * 16 + quad * 4 + t][w] = se[i][t];
    }
    __syncthreads();
    if (tid < QQ) {
        statsM[(size_t)blk * QQ + tid] = qmax[tid];
        statsS[(size_t)blk * QQ + tid] = sse[tid][0] + sse[tid][1] + sse[tid][2] + sse[tid][3];
    }
    // global p-tile write (vectorized)
    for (int it = tid; it < 2048; it += 256) {
        int q = it >> 6, c = it & 63;
        f16x8 v = *(const f16x8*)(tile + q * 520 + c * 8);
        *(f16x8*)(s16 + ((size_t)((b * HH + h) * QQ + q)) * MM + mt * 512 + c * 8) = v;
    }
    // ---- PV: ctx^T[d][q] = sum_m V^T[d][m] P^T[m][q], per wave over its 128 m ----
    f32x4 acc2[2][4];
#pragma unroll
    for (int i = 0; i < 2; i++)
#pragma unroll
        for (int j = 0; j < 4; j++) acc2[i][j] = vzero;
    const f16* vbase = Vt + ((size_t)(b * 512 + h * 64 + lq)) * MM + mbase + quad * 8;
#pragma unroll
    for (int ks = 0; ks < 4; ks++) {
        f16x8 pb[2];
        pb[0] = *(const f16x8*)(tile + lq * 520 + w * 128 + ks * 32 + quad * 8);
        pb[1] = *(const f16x8*)(tile + (16 + lq) * 520 + w * 128 + ks * 32 + quad * 8);
        f16x8 va[4];
#pragma unroll
        for (int j = 0; j < 4; j++)
            va[j] = *(const f16x8*)(vbase + (size_t)(j * 16) * MM + ks * 32);
#pragma unroll
        for (int j = 0; j < 4; j++) {
            acc2[0][j] = __builtin_amdgcn_mfma_f32_16x16x32_f16(va[j], pb[0], acc2[0][j], 0, 0, 0);
            acc2[1][j] = __builtin_amdgcn_mfma_f32_16x16x32_f16(va[j], pb[1], acc2[1][j], 0, 0, 0);
        }
    }
    // lane holds D[d = j*16+quad*4+t][q = i*16+lq]; reduce over 4 waves via LDS atomics
#pragma unroll
    for (int i = 0; i < 2; i++)
#pragma unroll
        for (int j = 0; j < 4; j++)
#pragma unroll
            for (int t = 0; t < 4; t++)
                atomicAdd(&ctile[(i * 16 + lq) * HDD + j * 16 + quad * 4 + t], acc2[i][j][t]);
    __syncthreads();
    {
        f32x4* cd = (f32x4*)(cp + ((size_t)((b * HH + h) * 16 + mt)) * (QQ * HDD));
        const f32x4* cs = (const f32x4*)ctile;
        for (int i = tid; i < QQ * HDD / 4; i += 256) cd[i] = cs[i];
    }
}

// ---------------- K11: chunk-combine + readouts GEMM + gate + LN (out 0)
//                       + fused attention head-mean (out 1) ----------------
__global__ __launch_bounds__(256) void k_outln(const float* __restrict__ cp,
                                               const float* __restrict__ statsM,
                                               const float* __restrict__ statsS,
                                               const f16* __restrict__ s16,
                                               const float* __restrict__ out_w,
                                               const float* __restrict__ out_b,
                                               const float* __restrict__ gates,
                                               const float* __restrict__ ln_g,
                                               const float* __restrict__ ln_b,
                                               float* __restrict__ out0,
                                               float* __restrict__ attn_out) {
    __shared__ float cr[DD];
    __shared__ float cM[128], cS[128], sMh[8], siL[8], wgt[128];
    __shared__ float sred[4], sred2[4];
    int bq = blockIdx.x, t = threadIdx.x;
    int b = bq >> 5, q = bq & 31;
    if (t < 128) {
        int h = t >> 4, c = t & 15;
        size_t sidx = (size_t)(((b * HH + h) * 16 + c)) * QQ + q;
        cM[t] = statsM[sidx];
        cS[t] = statsS[sidx];
    }
    __syncthreads();
    if (t < 8) {
        float M = NEG_INF;
#pragma unroll
        for (int c = 0; c < 16; c++) M = fmaxf(M, cM[t * 16 + c]);
        float L = 0.f;
#pragma unroll
        for (int c = 0; c < 16; c++) L += cS[t * 16 + c] * __expf(cM[t * 16 + c] - M);
        sMh[t] = M;
        siL[t] = 1.0f / L;
    }
    __syncthreads();
    if (t < 128) wgt[t] = __expf(cM[t] - sMh[t >> 4]) * siL[t >> 4];
    __syncthreads();
    // combine 16 chunks with weights: cr[d] = sum_c wgt[h(d)][c] * cp[b,h,c,q,d']
    int h0 = t >> 6, h1 = h0 + 4;
    int dl = t & 63;
    const float* cp0 = cp + ((size_t)((b * HH + h0) * 16)) * (QQ * HDD) + q * HDD + dl;
    const float* cp1 = cp + ((size_t)((b * HH + h1) * 16)) * (QQ * HDD) + q * HDD + dl;
    float c0 = 0.f, c1 = 0.f;
#pragma unroll
    for (int c = 0; c < 16; c++) {
        c0 += cp0[(size_t)c * (QQ * HDD)] * wgt[h0 * 16 + c];
        c1 += cp1[(size_t)c * (QQ * HDD)] * wgt[h1 * 16 + c];
    }
    cr[t] = c0;
    cr[t + 256] = c1;
    __syncthreads();
    float g = gates[bq];
    const f32x4* cv = (const f32x4*)cr;
    float r[2];
#pragma unroll
    for (int jj = 0; jj < 2; jj++) {
        int j = t + jj * 256;
        const f32x4* wv = (const f32x4*)(out_w + (size_t)j * DD);
        float acc = 0.f;
#pragma unroll 4
        for (int k = 0; k < DD / 4; k++) {
            f32x4 wq = wv[k], cq = cv[k];
            acc += wq.x * cq.x + wq.y * cq.y + wq.z * cq.z + wq.w * cq.w;
        }
        r[jj] = (acc + out_b[j]) * g;
    }
    float s1 = r[0] + r[1];
    float s2 = r[0] * r[0] + r[1] * r[1];
    for (int off = 32; off; off >>= 1) {
        s1 += __shfl_xor(s1, off, 64);
        s2 += __shfl_xor(s2, off, 64);
    }
    int wid = t >> 6;
    if ((t & 63) == 0) { sred[wid] = s1; sred2[wid] = s2; }
    __syncthreads();
    float S1 = sred[0] + sred[1] + sred[2] + sred[3];
    float S2 = sred2[0] + sred2[1] + sred2[2] + sred2[3];
    float mu = S1 * (1.0f / DD);
    float var = S2 * (1.0f / DD) - mu * mu;
    float rs = rsqrtf(var + LN_EPS);
#pragma unroll
    for (int jj = 0; jj < 2; jj++) {
        int j = t + jj * 256;
        out0[(size_t)bq * DD + j] = (r[jj] - mu) * rs * ln_g[j] + ln_b[j];
    }
    // ---- fused attention head-mean: attn[b,q,m] = (1/H) sum_h p[h,q,m]*wgt[h,c(m)]
#pragma unroll
    for (int ms = 0; ms < 4; ms++) {
        int m0 = ms * 2048 + t * 8;
        int cloc = ms * 4 + (t >> 6);
        float am[8];
#pragma unroll
        for (int e = 0; e < 8; e++) am[e] = 0.f;
#pragma unroll
        for (int h = 0; h < HH; h++) {
            f16x8 v = *(const f16x8*)(s16 + ((size_t)((b * HH + h) * QQ + q)) * MM + m0);
            float wc = wgt[h * 16 + cloc];
#pragma unroll
            for (int e = 0; e < 8; e++) am[e] += (float)v[e] * wc;
        }
        float* ao = attn_out + (size_t)bq * MM + m0;
        f32x4 o0 = {am[0] * 0.125f, am[1] * 0.125f, am[2] * 0.125f, am[3] * 0.125f};
        f32x4 o1 = {am[4] * 0.125f, am[5] * 0.125f, am[6] * 0.125f, am[7] * 0.125f};
        *(f32x4*)ao = o0;
        *(f32x4*)(ao + 4) = o1;
    }
}

extern "C" void kernel_launch(void* const* d_in, const int* in_sizes, int n_in,
                              void* d_out, int out_size, void* d_ws, size_t ws_size,
                              hipStream_t stream) {
    const float* memory  = (const float*)d_in[0];
    const float* context = (const float*)d_in[1];
    const int*   mask    = (const int*)d_in[2];
    const float* qp      = (const float*)d_in[3];
    const float* ctx_w   = (const float*)d_in[4];
    const float* ctx_b   = (const float*)d_in[5];
    const float* in_w    = (const float*)d_in[6];
    const float* in_b    = (const float*)d_in[7];
    const float* out_w   = (const float*)d_in[8];
    const float* out_b   = (const float*)d_in[9];
    const float* ln_g    = (const float*)d_in[10];
    const float* ln_b    = (const float*)d_in[11];
    const float* gate_w  = (const float*)d_in[12];
    const float* gate_b  = (const float*)d_in[13];

    float* out       = (float*)d_out;
    float* out_ln    = out;                       // (B,Q,D)   131072
    float* out_attn  = out + 131072;              // (B,Q,M)   2097152
    float* out_gates = out + 131072 + 2097152;    // (B,Q)     256
    float* out_q     = out_gates + 256;           // (B,Q,D)   131072

    char* ws = (char*)d_ws;
    bf16*  memB   = (bf16*)ws;                        // [0,64MB); dead after gemm
    f16*   s16    = (f16*)ws;                         // alias: 33.5 MB p-tiles
    float* cp     = (float*)(ws + 35651584);          // 8.4 MB ctx partials (in dead memB)
    bf16*  kvK    = (bf16*)(ws + 67108864);           // 64 MB head-major [b][h][m][64]
    f16*   Vt     = (f16*)(ws + 134217728);           // 64 MB f16 [b][hd][m]
    bf16*  kvwB   = (bf16*)(ws + 201326592);          // 256 KB (dead before statsM written)
    float* statsM = (float*)(ws + 201588736);         // 128 KB
    float* statsS = (float*)(ws + 201719808);         // 128 KB
    float* qh     = (float*)(ws + 202375168);         // 512 KB

    k_front<<<64, 512, 0, stream>>>(context, ctx_w, ctx_b, qp, gate_w, gate_b, out_q, out_gates);
    k_qh<<<64, 256, 0, stream>>>(out_q, in_w, in_b, qh);
    k_cvt2<<<2048, 256, 0, stream>>>(memory, in_w + 262144, memB, kvwB);
    k_gemm_kv<<<1024, 512, 0, stream>>>(memB, kvwB, in_b, kvK, Vt);
    k_scores<<<1024, 256, 0, stream>>>(qh, kvK, Vt, mask, s16, statsM, statsS, cp);
    k_outln<<<BB * QQ, 256, 0, stream>>>(cp, statsM, statsS, s16, out_w, out_b, out_gates,
                                         ln_g, ln_b, out_ln, out_attn);
}

// Round 6
// 477.301 us; speedup vs baseline: 1.0037x; 1.0037x over previous
//
#include <hip/hip_runtime.h>
#include <cstdint>

#define BB 8
#define MM 8192
#define SS 128
#define DD 512
#define QQ 32
#define HH 8
#define HDD 64
#define LN_EPS 1e-5f

typedef __bf16 bf16;
typedef _Float16 f16;
typedef __attribute__((ext_vector_type(8))) __bf16 bf16x8;
typedef __attribute__((ext_vector_type(4))) __bf16 bf16x4;
typedef __attribute__((ext_vector_type(8))) _Float16 f16x8;
typedef __attribute__((ext_vector_type(4))) float f32x4;

#define NEG_INF (-__builtin_inff())

// ---------------- K1: fused pooled + queries(out3) + gates(out2) ----------------
__global__ __launch_bounds__(512) void k_front(const float* __restrict__ ctx,
                                               const float* __restrict__ ctx_w,
                                               const float* __restrict__ ctx_b,
                                               const float* __restrict__ qp,
                                               const float* __restrict__ gate_w,
                                               const float* __restrict__ gate_b,
                                               float* __restrict__ q_out,
                                               float* __restrict__ gates_out) {
    __shared__ float pl[DD];
    __shared__ float scratch[512];
    __shared__ float proj[64];
    int blk = blockIdx.x;
    int b = blk >> 3, js = blk & 7;
    int t = threadIdx.x;
    const float* p = ctx + (size_t)b * SS * DD + t;
    float s = 0.f;
#pragma unroll 8
    for (int i = 0; i < SS; i++) s += p[(size_t)i * DD];
    pl[t] = s * (1.0f / SS);
    __syncthreads();
    int r = js * 64 + (t & 63), ks = t >> 6;
    {
        const f32x4* wr = (const f32x4*)(ctx_w + (size_t)r * DD + ks * 64);
        const f32x4* pv = (const f32x4*)(pl + ks * 64);
        float a = 0.f;
#pragma unroll
        for (int k = 0; k < 16; k++) {
            f32x4 w = wr[k], pp = pv[k];
            a += w.x * pp.x + w.y * pp.y + w.z * pp.z + w.w * pp.w;
        }
        scratch[t] = a;
    }
    __syncthreads();
    if (t < 64) {
        float sum = ctx_b[js * 64 + t];
#pragma unroll
        for (int s8 = 0; s8 < 8; s8++) sum += scratch[t + 64 * s8];
        proj[t] = sum;
    }
    __syncthreads();
    int col = js * 64 + (t & 63);
    float pr = proj[t & 63];
#pragma unroll
    for (int qq = 0; qq < 4; qq++) {
        int q = (t >> 6) * 4 + qq;
        q_out[((size_t)(b * QQ + q)) * DD + col] = qp[q * DD + col] + pr;
    }
    if (js == 0 && t < QQ) {
        const f32x4* gw = (const f32x4*)(gate_w + (size_t)t * DD);
        const f32x4* pv = (const f32x4*)pl;
        float ga = 0.f;
#pragma unroll 8
        for (int k = 0; k < DD / 4; k++) {
            f32x4 w = gw[k], pp = pv[k];
            ga += w.x * pp.x + w.y * pp.y + w.z * pp.z + w.w * pp.w;
        }
        gates_out[b * QQ + t] = 1.0f / (1.0f + __expf(-(ga + gate_b[t])));
    }
}

// ---------------- K4: qh = 0.125 * (queries @ wq^T + bq) ----------------
__global__ __launch_bounds__(256) void k_qh(const float* __restrict__ q_in,
                                            const float* __restrict__ in_w,
                                            const float* __restrict__ in_b,
                                            float* __restrict__ qh) {
    __shared__ float qr[QQ * DD];  // 64 KB
    int blk = blockIdx.x;
    int b = blk >> 3, js = blk & 7;
    int t = threadIdx.x;
    const f32x4* src = (const f32x4*)(q_in + (size_t)b * QQ * DD);
    f32x4* dst = (f32x4*)qr;
    for (int i = t; i < QQ * DD / 4; i += 256) dst[i] = src[i];
    __syncthreads();
    int j = js * 64 + (t & 63);
    int qg = t >> 6;
    const f32x4* wv = (const f32x4*)(in_w + (size_t)j * DD);
    float acc[8];
#pragma unroll
    for (int e = 0; e < 8; e++) acc[e] = 0.f;
    for (int k = 0; k < DD / 4; k++) {
        f32x4 w = wv[k];
#pragma unroll
        for (int e = 0; e < 8; e++) {
            f32x4 qq = ((const f32x4*)qr)[(qg * 8 + e) * (DD / 4) + k];
            acc[e] += w.x * qq.x + w.y * qq.y + w.z * qq.z + w.w * qq.w;
        }
    }
    float bias = in_b[j];
#pragma unroll
    for (int e = 0; e < 8; e++) {
        int q = qg * 8 + e;
        qh[((size_t)(b * QQ + q)) * DD + j] = 0.125f * (acc[e] + bias);
    }
}

// ---------------- K5: combined fp32->bf16 cast (memory + KV weights, one launch) --
#define N4_MEM 8388608
#define N4_W   131072
__global__ __launch_bounds__(256) void k_cvt2(const float* __restrict__ mem,
                                              const float* __restrict__ wsrc,
                                              bf16* __restrict__ memB,
                                              bf16* __restrict__ kvwB) {
    int stride = gridDim.x * blockDim.x;
    for (int i = blockIdx.x * blockDim.x + threadIdx.x; i < N4_MEM + N4_W; i += stride) {
        if (i < N4_MEM) {
            f32x4 v = ((const f32x4*)mem)[i];
            bf16x4 o;
            o.x = (bf16)v.x; o.y = (bf16)v.y; o.z = (bf16)v.z; o.w = (bf16)v.w;
            ((bf16x4*)memB)[i] = o;
        } else {
            int j = i - N4_MEM;
            f32x4 v = ((const f32x4*)wsrc)[j];
            bf16x4 o;
            o.x = (bf16)v.x; o.y = (bf16)v.y; o.z = (bf16)v.z; o.w = (bf16)v.w;
            ((bf16x4*)kvwB)[j] = o;
        }
    }
}

#define GLOAD(gp, lp)                                                                   \
    __builtin_amdgcn_global_load_lds((const __attribute__((address_space(1))) void*)(gp), \
                                     (__attribute__((address_space(3))) void*)(lp), 16, 0, 0)

// ---------------- K7: KV GEMM (proven 92us structure, split into 2 launches) ------
// 256x256 tile, BK=64, 512 threads (8 waves). global_load_lds staging both A,B.
// Counted-vmcnt pipeline; outputs K head-major [b][h][m][64] bf16; Vt [b][hd][m] f16.
// moff selects bm half (0: bm 0..127, 512: bm 128..255) so each launch is 512 blocks
// -> surfaces the true #2 kernel in rocprof top-5 (observability).
__global__ __launch_bounds__(512, 2) void k_gemm_kv(const bf16* __restrict__ A,
                                                    const bf16* __restrict__ Bw,
                                                    const float* __restrict__ in_b,
                                                    bf16* __restrict__ Kh,
                                                    f16* __restrict__ Vt,
                                                    int moff) {
    __shared__ __align__(16) bf16 sm[65536];  // 128 KB: 2 x [A 16384 | B 16384]
    const int tid = threadIdx.x;
    const int w = tid >> 6, l = tid & 63;
    const int wm = w >> 2, wn = w & 3;
    const int lq = l & 15, quad = l >> 4, lx = l & 7;
    const int lr = l >> 3, gc = (l & 7) ^ lr;
    const int sb = (w >> 1) * 8 + (w & 1) * 2;

    const int bid = blockIdx.x;                           // 512 blocks
    const int swz = (bid & 7) * 64 + (bid >> 3) + moff;   // XCD-contiguous chunks
    const int bm = swz >> 2, bn = swz & 3;

    const bf16* aPtr = A + (size_t)(bm * 256 + w * 8 + lr) * 512 + gc * 8;
    const bf16* bPtr = Bw + (size_t)(bn * 256 + sb * 8 + lr) * 512 + gc * 8;

    // prologue: tile 0 into buf 0. A x4, then B-low x2, then B-high x2.
#pragma unroll
    for (int p = 0; p < 4; p++) GLOAD(aPtr + p * 32768, sm + (p * 8 + w) * 512);
#pragma unroll
    for (int p = 0; p < 4; p++) {
        GLOAD(bPtr + ((p & 1) * 8 + (p >> 1) * 32) * 512,
              sm + 16384 + (sb + (p & 1) + (p >> 1) * 4) * 512);
        if (p == 1) __builtin_amdgcn_sched_barrier(0);
    }
    aPtr += 64;
    bPtr += 64;

    const f32x4 vzero = {0.f, 0.f, 0.f, 0.f};
    f32x4 acc[8][4];
#pragma unroll
    for (int i = 0; i < 8; i++)
#pragma unroll
        for (int j = 0; j < 4; j++) acc[i][j] = vzero;

#pragma unroll
    for (int T = 0; T < 8; T++) {
        bf16* Ab = sm + (T & 1) * 32768;
        bf16* Bb = Ab + 16384;
        bf16* AbN = sm + ((T + 1) & 1) * 32768;
        bf16* BbN = AbN + 16384;
        const bool pf = (T < 7);

        // ===== phase 0: A-frags + B cols 0,1; prefetch A(T+1) =====
        asm volatile("s_waitcnt vmcnt(2)" ::: "memory");
        __builtin_amdgcn_s_barrier();
        bf16x8 af[8][2], b01[2][2];
        {
            const int c0 = (quad ^ lx) << 3;
#pragma unroll
            for (int i = 0; i < 8; i++) {
                const bf16* rp = Ab + (wm * 128 + i * 16 + lq) * 64;
                af[i][0] = *(const bf16x8*)(rp + c0);
                af[i][1] = *(const bf16x8*)(rp + (c0 ^ 32));
            }
#pragma unroll
            for (int j = 0; j < 2; j++) {
                const bf16* rp = Bb + (wn * 64 + j * 16 + lq) * 64;
                b01[j][0] = *(const bf16x8*)(rp + c0);
                b01[j][1] = *(const bf16x8*)(rp + (c0 ^ 32));
            }
        }
        if (pf) {
#pragma unroll
            for (int p = 0; p < 4; p++) GLOAD(aPtr + p * 32768, AbN + (p * 8 + w) * 512);
            aPtr += 64;
        }
        __builtin_amdgcn_s_setprio(1);
#pragma unroll
        for (int i = 0; i < 8; i++)
#pragma unroll
            for (int j = 0; j < 2; j++) {
                acc[i][j] = __builtin_amdgcn_mfma_f32_16x16x32_bf16(af[i][0], b01[j][0], acc[i][j], 0, 0, 0);
                acc[i][j] = __builtin_amdgcn_mfma_f32_16x16x32_bf16(af[i][1], b01[j][1], acc[i][j], 0, 0, 0);
            }
        __builtin_amdgcn_s_setprio(0);

        // ===== phase 1: B cols 2,3; prefetch B(T+1) =====
        if (pf) {
            asm volatile("s_waitcnt vmcnt(4)" ::: "memory");
        } else {
            asm volatile("s_waitcnt vmcnt(0)" ::: "memory");
        }
        __builtin_amdgcn_s_barrier();
        bf16x8 b23[2][2];
        {
            const int c0 = (quad ^ lx) << 3;
#pragma unroll
            for (int j = 0; j < 2; j++) {
                const bf16* rp = Bb + (wn * 64 + 32 + j * 16 + lq) * 64;
                b23[j][0] = *(const bf16x8*)(rp + c0);
                b23[j][1] = *(const bf16x8*)(rp + (c0 ^ 32));
            }
        }
        if (pf) {
#pragma unroll
            for (int p = 0; p < 4; p++) {
                GLOAD(bPtr + ((p & 1) * 8 + (p >> 1) * 32) * 512,
                      BbN + (sb + (p & 1) + (p >> 1) * 4) * 512);
                if (p == 1) __builtin_amdgcn_sched_barrier(0);
            }
            bPtr += 64;
        }
        __builtin_amdgcn_s_setprio(1);
#pragma unroll
        for (int i = 0; i < 8; i++)
#pragma unroll
            for (int j = 0; j < 2; j++) {
                acc[i][2 + j] = __builtin_amdgcn_mfma_f32_16x16x32_bf16(af[i][0], b23[j][0], acc[i][2 + j], 0, 0, 0);
                acc[i][2 + j] = __builtin_amdgcn_mfma_f32_16x16x32_bf16(af[i][1], b23[j][1], acc[i][2 + j], 0, 0, 0);
            }
        __builtin_amdgcn_s_setprio(0);
    }

    // ---- epilogue through LDS: 4 quadrants of 128x128 in parallel (128 KB) ----
    __syncthreads();
    const int qn_w = wn >> 1;
    bf16* qt = sm + (((wm << 1) | qn_w) * 16384);
    const bool isV = (bn >= 2);
    if (!isV) {
        // K quadrants: row-major tile, col-chunk swizzled by row (bf16)
#pragma unroll
        for (int j = 0; j < 4; j++) {
            int cq = (wn & 1) * 64 + j * 16 + lq;
            float bias = in_b[512 + bn * 256 + qn_w * 128 + cq];
            int cc = cq >> 3, cl = cq & 7;
#pragma unroll
            for (int i = 0; i < 8; i++) {
                int rb = i * 16 + quad * 4;
#pragma unroll
                for (int t = 0; t < 4; t++) {
                    int r = rb + t;
                    qt[r * 128 + (((cc ^ (r & 15)) << 3) | cl)] = (bf16)(acc[i][j][t] + bias);
                }
            }
        }
        __syncthreads();
        for (int idx = tid; idx < 8192; idx += 512) {
            int qq2 = idx >> 11;
            int rr = (idx >> 4) & 127, ch2 = idx & 15;
            bf16x8 v = *(const bf16x8*)(sm + qq2 * 16384 + rr * 128 + ((ch2 ^ (rr & 15)) << 3));
            int m = bm * 256 + (qq2 >> 1) * 128 + rr;
            int cg = bn * 256 + (qq2 & 1) * 128 + ch2 * 8;
            int b = m >> 13, mloc = m & 8191;
            int h = cg >> 6, d = cg & 63;
            *(bf16x8*)(Kh + (((size_t)(b * 8 + h) * 8192 + mloc) << 6) + d) = v;
        }
    } else {
        // V quadrants: transposed tile, row-chunk swizzled by col (f16)
        f16* qth = (f16*)qt;
#pragma unroll
        for (int j = 0; j < 4; j++) {
            int cq = (wn & 1) * 64 + j * 16 + lq;
            float bias = in_b[512 + bn * 256 + qn_w * 128 + cq];
            int cs = cq & 15;
#pragma unroll
            for (int i = 0; i < 8; i++) {
                int rb = i * 16 + quad * 4;
#pragma unroll
                for (int t = 0; t < 4; t++) {
                    int r = rb + t;
                    qth[cq * 128 + ((((r >> 3) ^ cs) << 3) | (r & 7))] = (f16)(acc[i][j][t] + bias);
                }
            }
        }
        __syncthreads();
        for (int idx = tid; idx < 8192; idx += 512) {
            int qq2 = idx >> 11;
            int cq = (idx >> 4) & 127, ch2 = idx & 15;
            f16x8 v = *(const f16x8*)((const f16*)sm + qq2 * 16384 + cq * 128 + ((ch2 ^ (cq & 15)) << 3));
            int hd = (bn - 2) * 256 + (qq2 & 1) * 128 + cq;
            int m = bm * 256 + (qq2 >> 1) * 128 + ch2 * 8;
            int b = m >> 13, mloc = m & 8191;
            *(f16x8*)(Vt + ((size_t)(b * 512 + hd)) * MM + mloc) = v;
        }
    }
}
#undef GLOAD

// ---------------- K8: scores + softmax stats + fused PV partials ----------------
__global__ __launch_bounds__(256) void k_scores(const float* __restrict__ qh,
                                                const bf16* __restrict__ kvK,
                                                const f16* __restrict__ Vt,
                                                const int* __restrict__ mask,
                                                f16* __restrict__ s16,
                                                float* __restrict__ statsM,
                                                float* __restrict__ statsS,
                                                float* __restrict__ cp) {
    __shared__ __align__(16) f16 tile[QQ * 520];
    __shared__ float ctile[QQ * HDD];
    __shared__ float smx[QQ][4];
    __shared__ float sse[QQ][4];
    __shared__ float qmax[QQ];
    int blk = blockIdx.x;  // 1024 = B*H*16
    int mt = blk & 15, h = (blk >> 4) & 7, b = blk >> 7;
    int tid = threadIdx.x, w = tid >> 6, l = tid & 63;
    int lq = l & 15, quad = l >> 4;
    int mbase = mt * 512 + w * 128;

    for (int i = tid; i < QQ * HDD; i += 256) ctile[i] = 0.f;

    bf16x8 af[2][2];
#pragma unroll
    for (int i = 0; i < 2; i++)
#pragma unroll
        for (int s = 0; s < 2; s++) {
            const float* qp = qh + ((size_t)(b * QQ + i * 16 + lq)) * DD + h * 64 + s * 32 + quad * 8;
            f32x4 q0 = *(const f32x4*)qp;
            f32x4 q1 = *(const f32x4*)(qp + 4);
            bf16x8 v;
            v[0] = (bf16)q0.x; v[1] = (bf16)q0.y; v[2] = (bf16)q0.z; v[3] = (bf16)q0.w;
            v[4] = (bf16)q1.x; v[5] = (bf16)q1.y; v[6] = (bf16)q1.z; v[7] = (bf16)q1.w;
            af[i][s] = v;
        }

    const f32x4 vzero = {0.f, 0.f, 0.f, 0.f};
    f32x4 acc[2][8];
#pragma unroll
    for (int i = 0; i < 2; i++)
#pragma unroll
        for (int n = 0; n < 8; n++) acc[i][n] = vzero;

#pragma unroll
    for (int n = 0; n < 8; n++) {
        int m = mbase + n * 16 + lq;
        const bf16* kp = kvK + (((size_t)(b * HH + h) * MM + m) << 6) + quad * 8;
        bf16x8 b0 = *(const bf16x8*)kp;
        bf16x8 b1 = *(const bf16x8*)(kp + 32);
#pragma unroll
        for (int i = 0; i < 2; i++) {
            acc[i][n] = __builtin_amdgcn_mfma_f32_16x16x32_bf16(af[i][0], b0, acc[i][n], 0, 0, 0);
            acc[i][n] = __builtin_amdgcn_mfma_f32_16x16x32_bf16(af[i][1], b1, acc[i][n], 0, 0, 0);
        }
    }
#pragma unroll
    for (int n = 0; n < 8; n++) {
        int mv = mask[b * MM + mbase + n * 16 + lq];
        if (!mv) {
#pragma unroll
            for (int i = 0; i < 2; i++)
#pragma unroll
                for (int t = 0; t < 4; t++) acc[i][n][t] = NEG_INF;
        }
    }
    float mx[2][4];
#pragma unroll
    for (int i = 0; i < 2; i++)
#pragma unroll
        for (int t = 0; t < 4; t++) {
            float m = acc[i][0][t];
#pragma unroll
            for (int n = 1; n < 8; n++) m = fmaxf(m, acc[i][n][t]);
            mx[i][t] = m;
        }
#pragma unroll
    for (int off = 1; off < 16; off <<= 1)
#pragma unroll
        for (int i = 0; i < 2; i++)
#pragma unroll
            for (int t = 0; t < 4; t++) mx[i][t] = fmaxf(mx[i][t], __shfl_xor(mx[i][t], off, 64));
    if (lq == 0) {
#pragma unroll
        for (int i = 0; i < 2; i++)
#pragma unroll
            for (int t = 0; t < 4; t++) smx[i * 16 + quad * 4 + t][w] = mx[i][t];
    }
    __syncthreads();
    if (tid < QQ) qmax[tid] = fmaxf(fmaxf(smx[tid][0], smx[tid][1]), fmaxf(smx[tid][2], smx[tid][3]));
    __syncthreads();
    // p = exp(s - M_c): store to tile (f16) AND accumulate row-sum
    float se[2][4];
#pragma unroll
    for (int i = 0; i < 2; i++)
#pragma unroll
        for (int t = 0; t < 4; t++) {
            int qrow = i * 16 + quad * 4 + t;
            float qm = qmax[qrow];
            float s = 0.f;
#pragma unroll
            for (int n = 0; n < 8; n++) {
                float p = __expf(acc[i][n][t] - qm);
                s += p;
                tile[qrow * 520 + w * 128 + n * 16 + lq] = (f16)p;
            }
            se[i][t] = s;
        }
#pragma unroll
    for (int off = 1; off < 16; off <<= 1)
#pragma unroll
        for (int i = 0; i < 2; i++)
#pragma unroll
            for (int t = 0; t < 4; t++) se[i][t] += __shfl_xor(se[i][t], off, 64);
    if (lq == 0) {
#pragma unroll
        for (int i = 0; i < 2; i++)
#pragma unroll
            for (int t = 0; t < 4; t++) sse[i * 16 + quad * 4 + t][w] = se[i][t];
    }
    __syncthreads();
    if (tid < QQ) {
        statsM[(size_t)blk * QQ + tid] = qmax[tid];
        statsS[(size_t)blk * QQ + tid] = sse[tid][0] + sse[tid][1] + sse[tid][2] + sse[tid][3];
    }
    // global p-tile write (vectorized)
    for (int it = tid; it < 2048; it += 256) {
        int q = it >> 6, c = it & 63;
        f16x8 v = *(const f16x8*)(tile + q * 520 + c * 8);
        *(f16x8*)(s16 + ((size_t)((b * HH + h) * QQ + q)) * MM + mt * 512 + c * 8) = v;
    }
    // ---- PV: ctx^T[d][q] = sum_m V^T[d][m] P^T[m][q], per wave over its 128 m ----
    f32x4 acc2[2][4];
#pragma unroll
    for (int i = 0; i < 2; i++)
#pragma unroll
        for (int j = 0; j < 4; j++) acc2[i][j] = vzero;
    const f16* vbase = Vt + ((size_t)(b * 512 + h * 64 + lq)) * MM + mbase + quad * 8;
#pragma unroll
    for (int ks = 0; ks < 4; ks++) {
        f16x8 pb[2];
        pb[0] = *(const f16x8*)(tile + lq * 520 + w * 128 + ks * 32 + quad * 8);
        pb[1] = *(const f16x8*)(tile + (16 + lq) * 520 + w * 128 + ks * 32 + quad * 8);
        f16x8 va[4];
#pragma unroll
        for (int j = 0; j < 4; j++)
            va[j] = *(const f16x8*)(vbase + (size_t)(j * 16) * MM + ks * 32);
#pragma unroll
        for (int j = 0; j < 4; j++) {
            acc2[0][j] = __builtin_amdgcn_mfma_f32_16x16x32_f16(va[j], pb[0], acc2[0][j], 0, 0, 0);
            acc2[1][j] = __builtin_amdgcn_mfma_f32_16x16x32_f16(va[j], pb[1], acc2[1][j], 0, 0, 0);
        }
    }
    // lane holds D[d = j*16+quad*4+t][q = i*16+lq]; reduce over 4 waves via LDS atomics
#pragma unroll
    for (int i = 0; i < 2; i++)
#pragma unroll
        for (int j = 0; j < 4; j++)
#pragma unroll
            for (int t = 0; t < 4; t++)
                atomicAdd(&ctile[(i * 16 + lq) * HDD + j * 16 + quad * 4 + t], acc2[i][j][t]);
    __syncthreads();
    {
        f32x4* cd = (f32x4*)(cp + ((size_t)((b * HH + h) * 16 + mt)) * (QQ * HDD));
        const f32x4* cs = (const f32x4*)ctile;
        for (int i = tid; i < QQ * HDD / 4; i += 256) cd[i] = cs[i];
    }
}

// ---------------- K11: chunk-combine + readouts GEMM + gate + LN (out 0)
//                       + fused attention head-mean (out 1) ----------------
__global__ __launch_bounds__(256) void k_outln(const float* __restrict__ cp,
                                               const float* __restrict__ statsM,
                                               const float* __restrict__ statsS,
                                               const f16* __restrict__ s16,
                                               const float* __restrict__ out_w,
                                               const float* __restrict__ out_b,
                                               const float* __restrict__ gates,
                                               const float* __restrict__ ln_g,
                                               const float* __restrict__ ln_b,
                                               float* __restrict__ out0,
                                               float* __restrict__ attn_out) {
    __shared__ float cr[DD];
    __shared__ float cM[128], cS[128], sMh[8], siL[8], wgt[128];
    __shared__ float sred[4], sred2[4];
    int bq = blockIdx.x, t = threadIdx.x;
    int b = bq >> 5, q = bq & 31;
    if (t < 128) {
        int h = t >> 4, c = t & 15;
        size_t sidx = (size_t)(((b * HH + h) * 16 + c)) * QQ + q;
        cM[t] = statsM[sidx];
        cS[t] = statsS[sidx];
    }
    __syncthreads();
    if (t < 8) {
        float M = NEG_INF;
#pragma unroll
        for (int c = 0; c < 16; c++) M = fmaxf(M, cM[t * 16 + c]);
        float L = 0.f;
#pragma unroll
        for (int c = 0; c < 16; c++) L += cS[t * 16 + c] * __expf(cM[t * 16 + c] - M);
        sMh[t] = M;
        siL[t] = 1.0f / L;
    }
    __syncthreads();
    if (t < 128) wgt[t] = __expf(cM[t] - sMh[t >> 4]) * siL[t >> 4];
    __syncthreads();
    // combine 16 chunks with weights: cr[d] = sum_c wgt[h(d)][c] * cp[b,h,c,q,d']
    int h0 = t >> 6, h1 = h0 + 4;
    int dl = t & 63;
    const float* cp0 = cp + ((size_t)((b * HH + h0) * 16)) * (QQ * HDD) + q * HDD + dl;
    const float* cp1 = cp + ((size_t)((b * HH + h1) * 16)) * (QQ * HDD) + q * HDD + dl;
    float c0 = 0.f, c1 = 0.f;
#pragma unroll
    for (int c = 0; c < 16; c++) {
        c0 += cp0[(size_t)c * (QQ * HDD)] * wgt[h0 * 16 + c];
        c1 += cp1[(size_t)c * (QQ * HDD)] * wgt[h1 * 16 + c];
    }
    cr[t] = c0;
    cr[t + 256] = c1;
    __syncthreads();
    float g = gates[bq];
    const f32x4* cv = (const f32x4*)cr;
    float r[2];
#pragma unroll
    for (int jj = 0; jj < 2; jj++) {
        int j = t + jj * 256;
        const f32x4* wv = (const f32x4*)(out_w + (size_t)j * DD);
        float acc = 0.f;
#pragma unroll 4
        for (int k = 0; k < DD / 4; k++) {
            f32x4 wq = wv[k], cq = cv[k];
            acc += wq.x * cq.x + wq.y * cq.y + wq.z * cq.z + wq.w * cq.w;
        }
        r[jj] = (acc + out_b[j]) * g;
    }
    float s1 = r[0] + r[1];
    float s2 = r[0] * r[0] + r[1] * r[1];
    for (int off = 32; off; off >>= 1) {
        s1 += __shfl_xor(s1, off, 64);
        s2 += __shfl_xor(s2, off, 64);
    }
    int wid = t >> 6;
    if ((t & 63) == 0) { sred[wid] = s1; sred2[wid] = s2; }
    __syncthreads();
    float S1 = sred[0] + sred[1] + sred[2] + sred[3];
    float S2 = sred2[0] + sred2[1] + sred2[2] + sred2[3];
    float mu = S1 * (1.0f / DD);
    float var = S2 * (1.0f / DD) - mu * mu;
    float rs = rsqrtf(var + LN_EPS);
#pragma unroll
    for (int jj = 0; jj < 2; jj++) {
        int j = t + jj * 256;
        out0[(size_t)bq * DD + j] = (r[jj] - mu) * rs * ln_g[j] + ln_b[j];
    }
    // ---- fused attention head-mean: attn[b,q,m] = (1/H) sum_h p[h,q,m]*wgt[h,c(m)]
#pragma unroll
    for (int ms = 0; ms < 4; ms++) {
        int m0 = ms * 2048 + t * 8;
        int cloc = ms * 4 + (t >> 6);
        float am[8];
#pragma unroll
        for (int e = 0; e < 8; e++) am[e] = 0.f;
#pragma unroll
        for (int h = 0; h < HH; h++) {
            f16x8 v = *(const f16x8*)(s16 + ((size_t)((b * HH + h) * QQ + q)) * MM + m0);
            float wc = wgt[h * 16 + cloc];
#pragma unroll
            for (int e = 0; e < 8; e++) am[e] += (float)v[e] * wc;
        }
        float* ao = attn_out + (size_t)bq * MM + m0;
        f32x4 o0 = {am[0] * 0.125f, am[1] * 0.125f, am[2] * 0.125f, am[3] * 0.125f};
        f32x4 o1 = {am[4] * 0.125f, am[5] * 0.125f, am[6] * 0.125f, am[7] * 0.125f};
        *(f32x4*)ao = o0;
        *(f32x4*)(ao + 4) = o1;
    }
}

extern "C" void kernel_launch(void* const* d_in, const int* in_sizes, int n_in,
                              void* d_out, int out_size, void* d_ws, size_t ws_size,
                              hipStream_t stream) {
    const float* memory  = (const float*)d_in[0];
    const float* context = (const float*)d_in[1];
    const int*   mask    = (const int*)d_in[2];
    const float* qp      = (const float*)d_in[3];
    const float* ctx_w   = (const float*)d_in[4];
    const float* ctx_b   = (const float*)d_in[5];
    const float* in_w    = (const float*)d_in[6];
    const float* in_b    = (const float*)d_in[7];
    const float* out_w   = (const float*)d_in[8];
    const float* out_b   = (const float*)d_in[9];
    const float* ln_g    = (const float*)d_in[10];
    const float* ln_b    = (const float*)d_in[11];
    const float* gate_w  = (const float*)d_in[12];
    const float* gate_b  = (const float*)d_in[13];

    float* out       = (float*)d_out;
    float* out_ln    = out;                       // (B,Q,D)   131072
    float* out_attn  = out + 131072;              // (B,Q,M)   2097152
    float* out_gates = out + 131072 + 2097152;    // (B,Q)     256
    float* out_q     = out_gates + 256;           // (B,Q,D)   131072

    char* ws = (char*)d_ws;
    bf16*  memB   = (bf16*)ws;                        // [0,64MB); dead after gemm
    f16*   s16    = (f16*)ws;                         // alias: 33.5 MB p-tiles
    float* cp     = (float*)(ws + 35651584);          // 8.4 MB ctx partials (in dead memB)
    bf16*  kvK    = (bf16*)(ws + 67108864);           // 64 MB head-major [b][h][m][64]
    f16*   Vt     = (f16*)(ws + 134217728);           // 64 MB f16 [b][hd][m]
    bf16*  kvwB   = (bf16*)(ws + 201326592);          // 256 KB (dead before statsM written)
    float* statsM = (float*)(ws + 201588736);         // 128 KB
    float* statsS = (float*)(ws + 201719808);         // 128 KB
    float* qh     = (float*)(ws + 202375168);         // 512 KB

    k_front<<<64, 512, 0, stream>>>(context, ctx_w, ctx_b, qp, gate_w, gate_b, out_q, out_gates);
    k_qh<<<64, 256, 0, stream>>>(out_q, in_w, in_b, qh);
    k_cvt2<<<2048, 256, 0, stream>>>(memory, in_w + 262144, memB, kvwB);
    k_gemm_kv<<<512, 512, 0, stream>>>(memB, kvwB, in_b, kvK, Vt, 0);
    k_gemm_kv<<<512, 512, 0, stream>>>(memB, kvwB, in_b, kvK, Vt, 512);
    k_scores<<<1024, 256, 0, stream>>>(qh, kvK, Vt, mask, s16, statsM, statsS, cp);
    k_outln<<<BB * QQ, 256, 0, stream>>>(cp, statsM, statsS, s16, out_w, out_b, out_gates,
                                         ln_g, ln_b, out_ln, out_attn);
}

// Round 7
// 460.138 us; speedup vs baseline: 1.0412x; 1.0373x over previous
//
#include <hip/hip_runtime.h>
#include <cstdint>

#define BB 8
#define MM 8192
#define SS 128
#define DD 512
#define QQ 32
#define HH 8
#define HDD 64
#define LN_EPS 1e-5f

typedef __bf16 bf16;
typedef _Float16 f16;
typedef __attribute__((ext_vector_type(8))) __bf16 bf16x8;
typedef __attribute__((ext_vector_type(4))) __bf16 bf16x4;
typedef __attribute__((ext_vector_type(8))) _Float16 f16x8;
typedef __attribute__((ext_vector_type(4))) float f32x4;

#define NEG_INF (-__builtin_inff())

// ---------------- K0: mask scan -> compact index, inverse index, counts ----------
// One block per batch. midx[b][j] = m of j-th valid row; pos[b][m] = j or -1;
// mv[b] = count, mv[8+b] = count rounded up to 512.
__global__ __launch_bounds__(256) void k_mask(const int* __restrict__ mask,
                                              int* __restrict__ midx,
                                              int* __restrict__ pos,
                                              int* __restrict__ mv) {
    __shared__ int wsum[4];
    __shared__ int base;
    int b = blockIdx.x, t = threadIdx.x;
    int lane = t & 63, w = t >> 6;
    if (t == 0) base = 0;
    __syncthreads();
    for (int pass = 0; pass < 32; pass++) {
        int m = pass * 256 + t;
        int v = mask[b * MM + m] ? 1 : 0;
        unsigned long long ball = __ballot(v != 0);
        int excl = __popcll(ball & ((1ULL << lane) - 1ULL));
        if (lane == 0) wsum[w] = __popcll(ball);
        __syncthreads();
        int woff = 0;
#pragma unroll
        for (int k = 0; k < 4; k++) woff += (k < w) ? wsum[k] : 0;
        int total = wsum[0] + wsum[1] + wsum[2] + wsum[3];
        int j = base + woff + excl;
        if (v) {
            midx[b * MM + j] = m;
            pos[b * MM + m] = j;
        } else {
            pos[b * MM + m] = -1;
        }
        __syncthreads();
        if (t == 0) base += total;
        __syncthreads();
    }
    if (t == 0) {
        mv[b] = base;
        mv[8 + b] = (base + 511) & ~511;
    }
}

// ---------------- K1: fused pooled + queries(out3) + gates(out2) ----------------
__global__ __launch_bounds__(512) void k_front(const float* __restrict__ ctx,
                                               const float* __restrict__ ctx_w,
                                               const float* __restrict__ ctx_b,
                                               const float* __restrict__ qp,
                                               const float* __restrict__ gate_w,
                                               const float* __restrict__ gate_b,
                                               float* __restrict__ q_out,
                                               float* __restrict__ gates_out) {
    __shared__ float pl[DD];
    __shared__ float scratch[512];
    __shared__ float proj[64];
    int blk = blockIdx.x;
    int b = blk >> 3, js = blk & 7;
    int t = threadIdx.x;
    const float* p = ctx + (size_t)b * SS * DD + t;
    float s = 0.f;
#pragma unroll 8
    for (int i = 0; i < SS; i++) s += p[(size_t)i * DD];
    pl[t] = s * (1.0f / SS);
    __syncthreads();
    int r = js * 64 + (t & 63), ks = t >> 6;
    {
        const f32x4* wr = (const f32x4*)(ctx_w + (size_t)r * DD + ks * 64);
        const f32x4* pv = (const f32x4*)(pl + ks * 64);
        float a = 0.f;
#pragma unroll
        for (int k = 0; k < 16; k++) {
            f32x4 w = wr[k], pp = pv[k];
            a += w.x * pp.x + w.y * pp.y + w.z * pp.z + w.w * pp.w;
        }
        scratch[t] = a;
    }
    __syncthreads();
    if (t < 64) {
        float sum = ctx_b[js * 64 + t];
#pragma unroll
        for (int s8 = 0; s8 < 8; s8++) sum += scratch[t + 64 * s8];
        proj[t] = sum;
    }
    __syncthreads();
    int col = js * 64 + (t & 63);
    float pr = proj[t & 63];
#pragma unroll
    for (int qq = 0; qq < 4; qq++) {
        int q = (t >> 6) * 4 + qq;
        q_out[((size_t)(b * QQ + q)) * DD + col] = qp[q * DD + col] + pr;
    }
    if (js == 0 && t < QQ) {
        const f32x4* gw = (const f32x4*)(gate_w + (size_t)t * DD);
        const f32x4* pv = (const f32x4*)pl;
        float ga = 0.f;
#pragma unroll 8
        for (int k = 0; k < DD / 4; k++) {
            f32x4 w = gw[k], pp = pv[k];
            ga += w.x * pp.x + w.y * pp.y + w.z * pp.z + w.w * pp.w;
        }
        gates_out[b * QQ + t] = 1.0f / (1.0f + __expf(-(ga + gate_b[t])));
    }
}

// ---------------- K4: qh = 0.125 * (queries @ wq^T + bq) ----------------
__global__ __launch_bounds__(256) void k_qh(const float* __restrict__ q_in,
                                            const float* __restrict__ in_w,
                                            const float* __restrict__ in_b,
                                            float* __restrict__ qh) {
    __shared__ float qr[QQ * DD];  // 64 KB
    int blk = blockIdx.x;
    int b = blk >> 3, js = blk & 7;
    int t = threadIdx.x;
    const f32x4* src = (const f32x4*)(q_in + (size_t)b * QQ * DD);
    f32x4* dst = (f32x4*)qr;
    for (int i = t; i < QQ * DD / 4; i += 256) dst[i] = src[i];
    __syncthreads();
    int j = js * 64 + (t & 63);
    int qg = t >> 6;
    const f32x4* wv = (const f32x4*)(in_w + (size_t)j * DD);
    float acc[8];
#pragma unroll
    for (int e = 0; e < 8; e++) acc[e] = 0.f;
    for (int k = 0; k < DD / 4; k++) {
        f32x4 w = wv[k];
#pragma unroll
        for (int e = 0; e < 8; e++) {
            f32x4 qq = ((const f32x4*)qr)[(qg * 8 + e) * (DD / 4) + k];
            acc[e] += w.x * qq.x + w.y * qq.y + w.z * qq.z + w.w * qq.w;
        }
    }
    float bias = in_b[j];
#pragma unroll
    for (int e = 0; e < 8; e++) {
        int q = qg * 8 + e;
        qh[((size_t)(b * QQ + q)) * DD + j] = 0.125f * (acc[e] + bias);
    }
}

// ---------------- K5: gather valid rows + fp32->bf16 cast (+ weights) ----------
// Blocks [0,2016): one wave per compact row slot; valid -> gather-convert,
// slack [Mv, Mvc) -> zero-fill. Blocks [2016,2048): KV weight conversion.
__global__ __launch_bounds__(256) void k_gather(const float* __restrict__ memf,
                                                const float* __restrict__ wsrc,
                                                const int* __restrict__ midx,
                                                const int* __restrict__ mv,
                                                bf16* __restrict__ memB,
                                                bf16* __restrict__ kvwB) {
    int blk = blockIdx.x, t = threadIdx.x;
    if (blk < 2016) {
        int w = t >> 6, lane = t & 63;
        for (int s = blk * 4 + w; s < BB * MM; s += 2016 * 4) {
            int b = s >> 13, j = s & 8191;
            if (j >= mv[8 + b]) continue;
            bf16x8 o;
            if (j < mv[b]) {
                int src = midx[b * MM + j];
                const f32x4* sp = (const f32x4*)(memf + ((size_t)(b * MM + src)) * DD + lane * 8);
                f32x4 v0 = sp[0], v1 = sp[1];
                o[0] = (bf16)v0.x; o[1] = (bf16)v0.y; o[2] = (bf16)v0.z; o[3] = (bf16)v0.w;
                o[4] = (bf16)v1.x; o[5] = (bf16)v1.y; o[6] = (bf16)v1.z; o[7] = (bf16)v1.w;
            } else {
#pragma unroll
                for (int e = 0; e < 8; e++) o[e] = (bf16)0.0f;
            }
            *(bf16x8*)(memB + ((size_t)(b * MM + j)) * DD + lane * 8) = o;
        }
    } else {
        for (int i = (blk - 2016) * 256 + t; i < 131072; i += 32 * 256) {
            f32x4 v = ((const f32x4*)wsrc)[i];
            bf16x4 o;
            o.x = (bf16)v.x; o.y = (bf16)v.y; o.z = (bf16)v.z; o.w = (bf16)v.w;
            ((bf16x4*)kvwB)[i] = o;
        }
    }
}

#define GLOAD(gp, lp)                                                                   \
    __builtin_amdgcn_global_load_lds((const __attribute__((address_space(1))) void*)(gp), \
                                     (__attribute__((address_space(3))) void*)(lp), 16, 0, 0)

// ---------------- K7: KV GEMM on compacted rows (proven 92us structure) ----------
// 256x256 tile, BK=64, 512 threads. Early-return for tiles beyond Mvc[b].
__global__ __launch_bounds__(512, 2) void k_gemm_kv(const bf16* __restrict__ A,
                                                    const bf16* __restrict__ Bw,
                                                    const float* __restrict__ in_b,
                                                    const int* __restrict__ mv,
                                                    bf16* __restrict__ Kh,
                                                    f16* __restrict__ Vt) {
    __shared__ __align__(16) bf16 sm[65536];  // 128 KB: 2 x [A 16384 | B 16384]
    const int tid = threadIdx.x;
    const int w = tid >> 6, l = tid & 63;
    const int wm = w >> 2, wn = w & 3;
    const int lq = l & 15, quad = l >> 4, lx = l & 7;
    const int lr = l >> 3, gc = (l & 7) ^ lr;
    const int sb = (w >> 1) * 8 + (w & 1) * 2;

    const int bid = blockIdx.x;                    // 1024 blocks
    const int swz = (bid & 7) * 128 + (bid >> 3);  // XCD-contiguous chunks
    const int bm = swz >> 2, bn = swz & 3;

    // compact-row early exit: rows for this tile start at (bm&31)*256 within batch
    if (((bm & 31) * 256) >= mv[8 + (bm >> 5)]) return;

    const bf16* aPtr = A + (size_t)(bm * 256 + w * 8 + lr) * 512 + gc * 8;
    const bf16* bPtr = Bw + (size_t)(bn * 256 + sb * 8 + lr) * 512 + gc * 8;

    // prologue: tile 0 into buf 0. A x4, then B-low x2, then B-high x2.
#pragma unroll
    for (int p = 0; p < 4; p++) GLOAD(aPtr + p * 32768, sm + (p * 8 + w) * 512);
#pragma unroll
    for (int p = 0; p < 4; p++) {
        GLOAD(bPtr + ((p & 1) * 8 + (p >> 1) * 32) * 512,
              sm + 16384 + (sb + (p & 1) + (p >> 1) * 4) * 512);
        if (p == 1) __builtin_amdgcn_sched_barrier(0);
    }
    aPtr += 64;
    bPtr += 64;

    const f32x4 vzero = {0.f, 0.f, 0.f, 0.f};
    f32x4 acc[8][4];
#pragma unroll
    for (int i = 0; i < 8; i++)
#pragma unroll
        for (int j = 0; j < 4; j++) acc[i][j] = vzero;

#pragma unroll
    for (int T = 0; T < 8; T++) {
        bf16* Ab = sm + (T & 1) * 32768;
        bf16* Bb = Ab + 16384;
        bf16* AbN = sm + ((T + 1) & 1) * 32768;
        bf16* BbN = AbN + 16384;
        const bool pf = (T < 7);

        // ===== phase 0: A-frags + B cols 0,1; prefetch A(T+1) =====
        asm volatile("s_waitcnt vmcnt(2)" ::: "memory");
        __builtin_amdgcn_s_barrier();
        bf16x8 af[8][2], b01[2][2];
        {
            const int c0 = (quad ^ lx) << 3;
#pragma unroll
            for (int i = 0; i < 8; i++) {
                const bf16* rp = Ab + (wm * 128 + i * 16 + lq) * 64;
                af[i][0] = *(const bf16x8*)(rp + c0);
                af[i][1] = *(const bf16x8*)(rp + (c0 ^ 32));
            }
#pragma unroll
            for (int j = 0; j < 2; j++) {
                const bf16* rp = Bb + (wn * 64 + j * 16 + lq) * 64;
                b01[j][0] = *(const bf16x8*)(rp + c0);
                b01[j][1] = *(const bf16x8*)(rp + (c0 ^ 32));
            }
        }
        if (pf) {
#pragma unroll
            for (int p = 0; p < 4; p++) GLOAD(aPtr + p * 32768, AbN + (p * 8 + w) * 512);
            aPtr += 64;
        }
        __builtin_amdgcn_s_setprio(1);
#pragma unroll
        for (int i = 0; i < 8; i++)
#pragma unroll
            for (int j = 0; j < 2; j++) {
                acc[i][j] = __builtin_amdgcn_mfma_f32_16x16x32_bf16(af[i][0], b01[j][0], acc[i][j], 0, 0, 0);
                acc[i][j] = __builtin_amdgcn_mfma_f32_16x16x32_bf16(af[i][1], b01[j][1], acc[i][j], 0, 0, 0);
            }
        __builtin_amdgcn_s_setprio(0);

        // ===== phase 1: B cols 2,3; prefetch B(T+1) =====
        if (pf) {
            asm volatile("s_waitcnt vmcnt(4)" ::: "memory");
        } else {
            asm volatile("s_waitcnt vmcnt(0)" ::: "memory");
        }
        __builtin_amdgcn_s_barrier();
        bf16x8 b23[2][2];
        {
            const int c0 = (quad ^ lx) << 3;
#pragma unroll
            for (int j = 0; j < 2; j++) {
                const bf16* rp = Bb + (wn * 64 + 32 + j * 16 + lq) * 64;
                b23[j][0] = *(const bf16x8*)(rp + c0);
                b23[j][1] = *(const bf16x8*)(rp + (c0 ^ 32));
            }
        }
        if (pf) {
#pragma unroll
            for (int p = 0; p < 4; p++) {
                GLOAD(bPtr + ((p & 1) * 8 + (p >> 1) * 32) * 512,
                      BbN + (sb + (p & 1) + (p >> 1) * 4) * 512);
                if (p == 1) __builtin_amdgcn_sched_barrier(0);
            }
            bPtr += 64;
        }
        __builtin_amdgcn_s_setprio(1);
#pragma unroll
        for (int i = 0; i < 8; i++)
#pragma unroll
            for (int j = 0; j < 2; j++) {
                acc[i][2 + j] = __builtin_amdgcn_mfma_f32_16x16x32_bf16(af[i][0], b23[j][0], acc[i][2 + j], 0, 0, 0);
                acc[i][2 + j] = __builtin_amdgcn_mfma_f32_16x16x32_bf16(af[i][1], b23[j][1], acc[i][2 + j], 0, 0, 0);
            }
        __builtin_amdgcn_s_setprio(0);
    }

    // ---- epilogue through LDS: 4 quadrants of 128x128 in parallel (128 KB) ----
    __syncthreads();
    const int qn_w = wn >> 1;
    bf16* qt = sm + (((wm << 1) | qn_w) * 16384);
    const bool isV = (bn >= 2);
    if (!isV) {
        // K quadrants: row-major tile, col-chunk swizzled by row (bf16)
#pragma unroll
        for (int j = 0; j < 4; j++) {
            int cq = (wn & 1) * 64 + j * 16 + lq;
            float bias = in_b[512 + bn * 256 + qn_w * 128 + cq];
            int cc = cq >> 3, cl = cq & 7;
#pragma unroll
            for (int i = 0; i < 8; i++) {
                int rb = i * 16 + quad * 4;
#pragma unroll
                for (int t = 0; t < 4; t++) {
                    int r = rb + t;
                    qt[r * 128 + (((cc ^ (r & 15)) << 3) | cl)] = (bf16)(acc[i][j][t] + bias);
                }
            }
        }
        __syncthreads();
        for (int idx = tid; idx < 8192; idx += 512) {
            int qq2 = idx >> 11;
            int rr = (idx >> 4) & 127, ch2 = idx & 15;
            bf16x8 v = *(const bf16x8*)(sm + qq2 * 16384 + rr * 128 + ((ch2 ^ (rr & 15)) << 3));
            int m = bm * 256 + (qq2 >> 1) * 128 + rr;
            int cg = bn * 256 + (qq2 & 1) * 128 + ch2 * 8;
            int b = m >> 13, mloc = m & 8191;
            int h = cg >> 6, d = cg & 63;
            *(bf16x8*)(Kh + (((size_t)(b * 8 + h) * 8192 + mloc) << 6) + d) = v;
        }
    } else {
        // V quadrants: transposed tile, row-chunk swizzled by col (f16)
        f16* qth = (f16*)qt;
#pragma unroll
        for (int j = 0; j < 4; j++) {
            int cq = (wn & 1) * 64 + j * 16 + lq;
            float bias = in_b[512 + bn * 256 + qn_w * 128 + cq];
            int cs = cq & 15;
#pragma unroll
            for (int i = 0; i < 8; i++) {
                int rb = i * 16 + quad * 4;
#pragma unroll
                for (int t = 0; t < 4; t++) {
                    int r = rb + t;
                    qth[cq * 128 + ((((r >> 3) ^ cs) << 3) | (r & 7))] = (f16)(acc[i][j][t] + bias);
                }
            }
        }
        __syncthreads();
        for (int idx = tid; idx < 8192; idx += 512) {
            int qq2 = idx >> 11;
            int cq = (idx >> 4) & 127, ch2 = idx & 15;
            f16x8 v = *(const f16x8*)((const f16*)sm + qq2 * 16384 + cq * 128 + ((ch2 ^ (cq & 15)) << 3));
            int hd = (bn - 2) * 256 + (qq2 & 1) * 128 + cq;
            int m = bm * 256 + (qq2 >> 1) * 128 + ch2 * 8;
            int b = m >> 13, mloc = m & 8191;
            *(f16x8*)(Vt + ((size_t)(b * 512 + hd)) * MM + mloc) = v;
        }
    }
}
#undef GLOAD

// ---------------- K8: scores + softmax stats + fused PV partials (compact m) -----
__global__ __launch_bounds__(256) void k_scores(const float* __restrict__ qh,
                                                const bf16* __restrict__ kvK,
                                                const f16* __restrict__ Vt,
                                                const int* __restrict__ mv,
                                                f16* __restrict__ s16,
                                                float* __restrict__ statsM,
                                                float* __restrict__ statsS,
                                                float* __restrict__ cp) {
    __shared__ __align__(16) f16 tile[QQ * 520];
    __shared__ float ctile[QQ * HDD];
    __shared__ float smx[QQ][4];
    __shared__ float sse[QQ][4];
    __shared__ float qmax[QQ];
    int blk = blockIdx.x;  // 1024 = B*H*16
    int mt = blk & 15, h = (blk >> 4) & 7, b = blk >> 7;
    int tid = threadIdx.x, w = tid >> 6, l = tid & 63;
    int lq = l & 15, quad = l >> 4;
    int Mvb = mv[b];
    if (mt * 512 >= Mvb) {  // empty chunk: stats only (uniform exit, no barriers)
        if (tid < QQ) {
            statsM[(size_t)blk * QQ + tid] = NEG_INF;
            statsS[(size_t)blk * QQ + tid] = 0.f;
        }
        return;
    }
    int mbase = mt * 512 + w * 128;

    for (int i = tid; i < QQ * HDD; i += 256) ctile[i] = 0.f;

    bf16x8 af[2][2];
#pragma unroll
    for (int i = 0; i < 2; i++)
#pragma unroll
        for (int s = 0; s < 2; s++) {
            const float* qp = qh + ((size_t)(b * QQ + i * 16 + lq)) * DD + h * 64 + s * 32 + quad * 8;
            f32x4 q0 = *(const f32x4*)qp;
            f32x4 q1 = *(const f32x4*)(qp + 4);
            bf16x8 v;
            v[0] = (bf16)q0.x; v[1] = (bf16)q0.y; v[2] = (bf16)q0.z; v[3] = (bf16)q0.w;
            v[4] = (bf16)q1.x; v[5] = (bf16)q1.y; v[6] = (bf16)q1.z; v[7] = (bf16)q1.w;
            af[i][s] = v;
        }

    const f32x4 vzero = {0.f, 0.f, 0.f, 0.f};
    f32x4 acc[2][8];
#pragma unroll
    for (int i = 0; i < 2; i++)
#pragma unroll
        for (int n = 0; n < 8; n++) acc[i][n] = vzero;

#pragma unroll
    for (int n = 0; n < 8; n++) {
        int m = mbase + n * 16 + lq;
        const bf16* kp = kvK + (((size_t)(b * HH + h) * MM + m) << 6) + quad * 8;
        bf16x8 b0 = *(const bf16x8*)kp;
        bf16x8 b1 = *(const bf16x8*)(kp + 32);
#pragma unroll
        for (int i = 0; i < 2; i++) {
            acc[i][n] = __builtin_amdgcn_mfma_f32_16x16x32_bf16(af[i][0], b0, acc[i][n], 0, 0, 0);
            acc[i][n] = __builtin_amdgcn_mfma_f32_16x16x32_bf16(af[i][1], b1, acc[i][n], 0, 0, 0);
        }
    }
    // bound-mask: compact columns >= Mv are dead (replaces the 2MB mask read)
#pragma unroll
    for (int n = 0; n < 8; n++) {
        if (mbase + n * 16 + lq >= Mvb) {
#pragma unroll
            for (int i = 0; i < 2; i++)
#pragma unroll
                for (int t = 0; t < 4; t++) acc[i][n][t] = NEG_INF;
        }
    }
    float mx[2][4];
#pragma unroll
    for (int i = 0; i < 2; i++)
#pragma unroll
        for (int t = 0; t < 4; t++) {
            float m = acc[i][0][t];
#pragma unroll
            for (int n = 1; n < 8; n++) m = fmaxf(m, acc[i][n][t]);
            mx[i][t] = m;
        }
#pragma unroll
    for (int off = 1; off < 16; off <<= 1)
#pragma unroll
        for (int i = 0; i < 2; i++)
#pragma unroll
            for (int t = 0; t < 4; t++) mx[i][t] = fmaxf(mx[i][t], __shfl_xor(mx[i][t], off, 64));
    if (lq == 0) {
#pragma unroll
        for (int i = 0; i < 2; i++)
#pragma unroll
            for (int t = 0; t < 4; t++) smx[i * 16 + quad * 4 + t][w] = mx[i][t];
    }
    __syncthreads();
    if (tid < QQ) qmax[tid] = fmaxf(fmaxf(smx[tid][0], smx[tid][1]), fmaxf(smx[tid][2], smx[tid][3]));
    __syncthreads();
    float se[2][4];
#pragma unroll
    for (int i = 0; i < 2; i++)
#pragma unroll
        for (int t = 0; t < 4; t++) {
            int qrow = i * 16 + quad * 4 + t;
            float qm = qmax[qrow];
            float s = 0.f;
#pragma unroll
            for (int n = 0; n < 8; n++) {
                float p = __expf(acc[i][n][t] - qm);
                s += p;
                tile[qrow * 520 + w * 128 + n * 16 + lq] = (f16)p;
            }
            se[i][t] = s;
        }
#pragma unroll
    for (int off = 1; off < 16; off <<= 1)
#pragma unroll
        for (int i = 0; i < 2; i++)
#pragma unroll
            for (int t = 0; t < 4; t++) se[i][t] += __shfl_xor(se[i][t], off, 64);
    if (lq == 0) {
#pragma unroll
        for (int i = 0; i < 2; i++)
#pragma unroll
            for (int t = 0; t < 4; t++) sse[i * 16 + quad * 4 + t][w] = se[i][t];
    }
    __syncthreads();
    if (tid < QQ) {
        statsM[(size_t)blk * QQ + tid] = qmax[tid];
        statsS[(size_t)blk * QQ + tid] = sse[tid][0] + sse[tid][1] + sse[tid][2] + sse[tid][3];
    }
    for (int it = tid; it < 2048; it += 256) {
        int q = it >> 6, c = it & 63;
        f16x8 v = *(const f16x8*)(tile + q * 520 + c * 8);
        *(f16x8*)(s16 + ((size_t)((b * HH + h) * QQ + q)) * MM + mt * 512 + c * 8) = v;
    }
    // ---- PV: ctx^T[d][q] = sum_m V^T[d][m] P^T[m][q] (V defined up to Mvc) ----
    f32x4 acc2[2][4];
#pragma unroll
    for (int i = 0; i < 2; i++)
#pragma unroll
        for (int j = 0; j < 4; j++) acc2[i][j] = vzero;
    const f16* vbase = Vt + ((size_t)(b * 512 + h * 64 + lq)) * MM + mbase + quad * 8;
#pragma unroll
    for (int ks = 0; ks < 4; ks++) {
        f16x8 pb[2];
        pb[0] = *(const f16x8*)(tile + lq * 520 + w * 128 + ks * 32 + quad * 8);
        pb[1] = *(const f16x8*)(tile + (16 + lq) * 520 + w * 128 + ks * 32 + quad * 8);
        f16x8 va[4];
#pragma unroll
        for (int j = 0; j < 4; j++)
            va[j] = *(const f16x8*)(vbase + (size_t)(j * 16) * MM + ks * 32);
#pragma unroll
        for (int j = 0; j < 4; j++) {
            acc2[0][j] = __builtin_amdgcn_mfma_f32_16x16x32_f16(va[j], pb[0], acc2[0][j], 0, 0, 0);
            acc2[1][j] = __builtin_amdgcn_mfma_f32_16x16x32_f16(va[j], pb[1], acc2[1][j], 0, 0, 0);
        }
    }
#pragma unroll
    for (int i = 0; i < 2; i++)
#pragma unroll
        for (int j = 0; j < 4; j++)
#pragma unroll
            for (int t = 0; t < 4; t++)
                atomicAdd(&ctile[(i * 16 + lq) * HDD + j * 16 + quad * 4 + t], acc2[i][j][t]);
    __syncthreads();
    {
        f32x4* cd = (f32x4*)(cp + ((size_t)((b * HH + h) * 16 + mt)) * (QQ * HDD));
        const f32x4* cs = (const f32x4*)ctile;
        for (int i = tid; i < QQ * HDD / 4; i += 256) cd[i] = cs[i];
    }
}

// ---------------- K11: chunk-combine + readouts GEMM + gate + LN (out 0)
//                       + compact attention head-mean -> tmp ----------------
__global__ __launch_bounds__(256) void k_outln(const float* __restrict__ cp,
                                               const float* __restrict__ statsM,
                                               const float* __restrict__ statsS,
                                               const f16* __restrict__ s16,
                                               const int* __restrict__ mv,
                                               const float* __restrict__ out_w,
                                               const float* __restrict__ out_b,
                                               const float* __restrict__ gates,
                                               const float* __restrict__ ln_g,
                                               const float* __restrict__ ln_b,
                                               float* __restrict__ out0,
                                               float* __restrict__ tmpA) {
    __shared__ float cr[DD];
    __shared__ float cM[128], cS[128], sMh[8], siL[8], wgt[128];
    __shared__ float sred[4], sred2[4];
    int bq = blockIdx.x, t = threadIdx.x;
    int b = bq >> 5, q = bq & 31;
    int Mvb = mv[b];
    if (t < 128) {
        int h = t >> 4, c = t & 15;
        size_t sidx = (size_t)(((b * HH + h) * 16 + c)) * QQ + q;
        cM[t] = statsM[sidx];
        cS[t] = statsS[sidx];
    }
    __syncthreads();
    if (t < 8) {
        float M = NEG_INF;
#pragma unroll
        for (int c = 0; c < 16; c++) M = fmaxf(M, cM[t * 16 + c]);
        float L = 0.f;
#pragma unroll
        for (int c = 0; c < 16; c++)
            if (cS[t * 16 + c] > 0.f) L += cS[t * 16 + c] * __expf(cM[t * 16 + c] - M);
        sMh[t] = M;
        siL[t] = 1.0f / L;
    }
    __syncthreads();
    if (t < 128) wgt[t] = (cS[t] > 0.f) ? __expf(cM[t] - sMh[t >> 4]) * siL[t >> 4] : 0.f;
    __syncthreads();
    // combine chunks (guard: empty-chunk cp is uninitialized poison)
    int h0 = t >> 6, h1 = h0 + 4;
    int dl = t & 63;
    const float* cp0 = cp + ((size_t)((b * HH + h0) * 16)) * (QQ * HDD) + q * HDD + dl;
    const float* cp1 = cp + ((size_t)((b * HH + h1) * 16)) * (QQ * HDD) + q * HDD + dl;
    float c0 = 0.f, c1 = 0.f;
#pragma unroll
    for (int c = 0; c < 16; c++) {
        float w0 = wgt[h0 * 16 + c], w1 = wgt[h1 * 16 + c];
        if (w0 > 0.f) c0 += cp0[(size_t)c * (QQ * HDD)] * w0;
        if (w1 > 0.f) c1 += cp1[(size_t)c * (QQ * HDD)] * w1;
    }
    cr[t] = c0;
    cr[t + 256] = c1;
    __syncthreads();
    float g = gates[bq];
    const f32x4* cv = (const f32x4*)cr;
    float r[2];
#pragma unroll
    for (int jj = 0; jj < 2; jj++) {
        int j = t + jj * 256;
        const f32x4* wv = (const f32x4*)(out_w + (size_t)j * DD);
        float acc = 0.f;
#pragma unroll 4
        for (int k = 0; k < DD / 4; k++) {
            f32x4 wq = wv[k], cq = cv[k];
            acc += wq.x * cq.x + wq.y * cq.y + wq.z * cq.z + wq.w * cq.w;
        }
        r[jj] = (acc + out_b[j]) * g;
    }
    float s1 = r[0] + r[1];
    float s2 = r[0] * r[0] + r[1] * r[1];
    for (int off = 32; off; off >>= 1) {
        s1 += __shfl_xor(s1, off, 64);
        s2 += __shfl_xor(s2, off, 64);
    }
    int wid = t >> 6;
    if ((t & 63) == 0) { sred[wid] = s1; sred2[wid] = s2; }
    __syncthreads();
    float S1 = sred[0] + sred[1] + sred[2] + sred[3];
    float S2 = sred2[0] + sred2[1] + sred2[2] + sred2[3];
    float mu = S1 * (1.0f / DD);
    float var = S2 * (1.0f / DD) - mu * mu;
    float rs = rsqrtf(var + LN_EPS);
#pragma unroll
    for (int jj = 0; jj < 2; jj++) {
        int j = t + jj * 256;
        out0[(size_t)bq * DD + j] = (r[jj] - mu) * rs * ln_g[j] + ln_b[j];
    }
    // ---- compact attention head-mean: tmpA[b,q,j] = (1/H) sum_h p[h,q,j]*wgt[h,c(j)]
#pragma unroll
    for (int ms = 0; ms < 4; ms++) {
        int j0 = ms * 2048 + t * 8;
        if (j0 >= Mvb) continue;
        int cloc = j0 >> 9;
        float am[8];
#pragma unroll
        for (int e = 0; e < 8; e++) am[e] = 0.f;
#pragma unroll
        for (int h = 0; h < HH; h++) {
            f16x8 v = *(const f16x8*)(s16 + ((size_t)((b * HH + h) * QQ + q)) * MM + j0);
            float wc = wgt[h * 16 + cloc];
#pragma unroll
            for (int e = 0; e < 8; e++) am[e] += (float)v[e] * wc;
        }
        float* ao = tmpA + (size_t)bq * MM + j0;
        f32x4 o0 = {am[0] * 0.125f, am[1] * 0.125f, am[2] * 0.125f, am[3] * 0.125f};
        f32x4 o1 = {am[4] * 0.125f, am[5] * 0.125f, am[6] * 0.125f, am[7] * 0.125f};
        *(f32x4*)ao = o0;
        *(f32x4*)(ao + 4) = o1;
    }
}

// ---------------- K12: scatter compact attention to (B,Q,M); masked -> 0 ---------
__global__ __launch_bounds__(256) void k_scatter(const float* __restrict__ tmpA,
                                                 const int* __restrict__ pos,
                                                 float* __restrict__ attn_out) {
    int idx = blockIdx.x * 256 + threadIdx.x;  // 524288 threads x 4 m
    int L = idx * 4;
    int bq = L >> 13, m = L & 8191;
    int b = bq >> 5;
    int4 p4 = *(const int4*)(pos + b * MM + m);
    const float* tb_ = tmpA + (size_t)bq * MM;
    f32x4 o;
    o.x = (p4.x >= 0) ? tb_[p4.x] : 0.f;
    o.y = (p4.y >= 0) ? tb_[p4.y] : 0.f;
    o.z = (p4.z >= 0) ? tb_[p4.z] : 0.f;
    o.w = (p4.w >= 0) ? tb_[p4.w] : 0.f;
    *(f32x4*)(attn_out + (size_t)bq * MM + m) = o;
}

extern "C" void kernel_launch(void* const* d_in, const int* in_sizes, int n_in,
                              void* d_out, int out_size, void* d_ws, size_t ws_size,
                              hipStream_t stream) {
    const float* memory  = (const float*)d_in[0];
    const float* context = (const float*)d_in[1];
    const int*   mask    = (const int*)d_in[2];
    const float* qp      = (const float*)d_in[3];
    const float* ctx_w   = (const float*)d_in[4];
    const float* ctx_b   = (const float*)d_in[5];
    const float* in_w    = (const float*)d_in[6];
    const float* in_b    = (const float*)d_in[7];
    const float* out_w   = (const float*)d_in[8];
    const float* out_b   = (const float*)d_in[9];
    const float* ln_g    = (const float*)d_in[10];
    const float* ln_b    = (const float*)d_in[11];
    const float* gate_w  = (const float*)d_in[12];
    const float* gate_b  = (const float*)d_in[13];

    float* out       = (float*)d_out;
    float* out_ln    = out;                       // (B,Q,D)   131072
    float* out_attn  = out + 131072;              // (B,Q,M)   2097152
    float* out_gates = out + 131072 + 2097152;    // (B,Q)     256
    float* out_q     = out_gates + 256;           // (B,Q,D)   131072

    char* ws = (char*)d_ws;
    bf16*  memB   = (bf16*)ws;                        // [0,64MB) compacted rows; dead after gemm
    f16*   s16    = (f16*)ws;                         // alias: 33.5 MB compact p-tiles
    float* cp     = (float*)(ws + 35651584);          // 8.4 MB ctx partials
    float* tmpA   = (float*)(ws + 44040192);          // 8.4 MB compact attn values
    bf16*  kvK    = (bf16*)(ws + 67108864);           // 64 MB head-major [b][h][m][64]
    f16*   Vt     = (f16*)(ws + 134217728);           // 64 MB f16 [b][hd][m]
    bf16*  kvwB   = (bf16*)(ws + 201326592);          // 256 KB
    float* statsM = (float*)(ws + 201588736);         // 128 KB
    float* statsS = (float*)(ws + 201719808);         // 128 KB
    float* qh     = (float*)(ws + 202375168);         // 512 KB
    int*   midx   = (int*)(ws + 202899456);           // 256 KB compact->orig m
    int*   pos    = (int*)(ws + 203161600);           // 256 KB orig->compact (-1 masked)
    int*   mv     = (int*)(ws + 203423744);           // [0..7]=Mv, [8..15]=ceil512(Mv)

    k_mask<<<8, 256, 0, stream>>>(mask, midx, pos, mv);
    k_front<<<64, 512, 0, stream>>>(context, ctx_w, ctx_b, qp, gate_w, gate_b, out_q, out_gates);
    k_qh<<<64, 256, 0, stream>>>(out_q, in_w, in_b, qh);
    k_gather<<<2048, 256, 0, stream>>>(memory, in_w + 262144, midx, mv, memB, kvwB);
    k_gemm_kv<<<1024, 512, 0, stream>>>(memB, kvwB, in_b, mv, kvK, Vt);
    k_scores<<<1024, 256, 0, stream>>>(qh, kvK, Vt, mv, s16, statsM, statsS, cp);
    k_outln<<<BB * QQ, 256, 0, stream>>>(cp, statsM, statsS, s16, mv, out_w, out_b, out_gates,
                                         ln_g, ln_b, out_ln, tmpA);
    k_scatter<<<2048, 256, 0, stream>>>(tmpA, pos, out_attn);
}